// Round 12
// baseline (314.030 us; speedup 1.0000x reference)
//
#include <hip/hip_runtime.h>
#include <hip/hip_bf16.h>

typedef float f4 __attribute__((ext_vector_type(4)));
typedef short s8 __attribute__((ext_vector_type(8)));
typedef short s4 __attribute__((ext_vector_type(4)));

__device__ __forceinline__ short f2bf(float f) {
  union { float f; unsigned u; } v; v.f = f;
  unsigned r = v.u + 0x7fffu + ((v.u >> 16) & 1u);
  return (short)(r >> 16);
}
// async global->LDS, 16B/lane; LDS dest = wave-uniform base + lane*16 (linear)
__device__ __forceinline__ void gl16(const short* g, short* l) {
  __builtin_amdgcn_global_load_lds(
      (const __attribute__((address_space(1))) unsigned*)g,
      (__attribute__((address_space(3))) unsigned*)l, 16, 0, 0);
}

// ---------------------------------------------------------------------------
// FUSED K/Q-GEMM + QK^T v3 — barrier-free, direct-global B-operands.
//  grid = 512 (2 blocks/CU), block = (b, sc in [0,16), hg); 4 slices x 64.
//  B-fragments (qT/xT) and A-fragments (weights) are loaded DIRECTLY from
//  global per wave: each wave-load touches 16 rows x 64 contiguous aligned
//  bytes -> same L2-line count as a coalesced load. The 4x in-block B
//  duplication is L2-absorbed. This deletes Bq/Bx LDS (120->48 KB), all
//  staging, all vmcnt asm, and ALL barriers: Qt/Kt rows are per-wave-owned
//  (wave w = head hg*4+w, rows w*48..w*48+47), so same-wave LDS ordering
//  (compiler lgkmcnt) is the only dependency. 2 waves/SIMD hide the
//  latency that 1-wave/SIMD R11 exposed. Register S-acc, non-atomic store.
// ---------------------------------------------------------------------------
__global__ __launch_bounds__(256, 2)
void kqs_k(const short* __restrict__ xT, const short* __restrict__ qT,
           const short* __restrict__ wkb, const short* __restrict__ wqb,
           float* __restrict__ Spart, float* __restrict__ ssq,
           float* __restrict__ ssk) {
  __shared__ __align__(16) short Qt[192 * 64];   // 24 KB, rows per-wave-owned
  __shared__ __align__(16) short Kt[192 * 64];   // 24 KB
  const int orig = blockIdx.x;
  const int xcd = orig & 7, ix = orig >> 3;      // ix in [0,64)
  const int pair = xcd * 32 + (ix >> 1);         // [0,256): (b, sc); hg-pair
  const int hg = ix & 1;                         //   shares XCD (L2 reuse)
  const int b = pair >> 4, sc = pair & 15;
  const int tid = threadIdx.x, lane = tid & 63, w = tid >> 6;
  const int l15 = lane & 15, lhi = lane >> 4;
  const int hl = w * 48;

  const short* qTb = qT + (long)b * 4096 * 192;
  const short* xTb = xT + (long)b * 4096 * 384;
  const short* wqw = wqb + (long)(hg * 192 + hl) * 192;
  const short* wkw = wkb + (long)(hg * 192 + hl) * 384;

  f4 Sacc[3][3];
#pragma unroll
  for (int i = 0; i < 3; ++i)
#pragma unroll
    for (int j = 0; j < 3; ++j) Sacc[i][j] = (f4){0.f, 0.f, 0.f, 0.f};
  float sqa[12], ska[12];
#pragma unroll
  for (int i = 0; i < 12; ++i) { sqa[i] = 0.f; ska[i] = 0.f; }

#pragma unroll 1
  for (int t = 0; t < 4; ++t) {
    const int s0 = sc * 256 + t * 64;

    // ---- phase 1Q: Qt[rows hl..hl+47][64] = wq @ qT-slice (K=192)
    {
      f4 acc[3][4];
#pragma unroll
      for (int i = 0; i < 3; ++i)
#pragma unroll
        for (int j = 0; j < 4; ++j) acc[i][j] = (f4){0.f, 0.f, 0.f, 0.f};
#pragma unroll
      for (int kk = 0; kk < 192; kk += 32) {
        s8 af[3], bf[4];
#pragma unroll
        for (int mi = 0; mi < 3; ++mi)
          af[mi] = *(const s8*)(wqw + (long)(mi * 16 + l15) * 192 + kk + lhi * 8);
#pragma unroll
        for (int ni = 0; ni < 4; ++ni)
          bf[ni] = *(const s8*)(qTb + (long)(s0 + ni * 16 + l15) * 192 +
                                kk + lhi * 8);
#pragma unroll
        for (int mi = 0; mi < 3; ++mi)
#pragma unroll
          for (int ni = 0; ni < 4; ++ni)
            acc[mi][ni] = __builtin_amdgcn_mfma_f32_16x16x32_bf16(
                af[mi], bf[ni], acc[mi][ni], 0, 0, 0);
      }
#pragma unroll
      for (int mi = 0; mi < 3; ++mi)
#pragma unroll
        for (int r = 0; r < 4; ++r) {
          const int row = hl + mi * 16 + lhi * 4 + r;
#pragma unroll
          for (int ni = 0; ni < 4; ++ni) {
            const int col = ni * 16 + l15;
            const float v = acc[mi][ni][r];
            Qt[row * 64 + (((col >> 3) ^ (row & 7)) << 3) + (col & 7)] =
                f2bf(v);
            sqa[mi * 4 + r] += v * v;
          }
        }
    }

    // ---- phase 1K: Kt[rows][64] = wk @ xT-slice (K=384)
    {
      f4 acc[3][4];
#pragma unroll
      for (int i = 0; i < 3; ++i)
#pragma unroll
        for (int j = 0; j < 4; ++j) acc[i][j] = (f4){0.f, 0.f, 0.f, 0.f};
#pragma unroll 4
      for (int kk = 0; kk < 384; kk += 32) {
        s8 af[3], bf[4];
#pragma unroll
        for (int mi = 0; mi < 3; ++mi)
          af[mi] = *(const s8*)(wkw + (long)(mi * 16 + l15) * 384 + kk + lhi * 8);
#pragma unroll
        for (int ni = 0; ni < 4; ++ni)
          bf[ni] = *(const s8*)(xTb + (long)(s0 + ni * 16 + l15) * 384 +
                                kk + lhi * 8);
#pragma unroll
        for (int mi = 0; mi < 3; ++mi)
#pragma unroll
          for (int ni = 0; ni < 4; ++ni)
            acc[mi][ni] = __builtin_amdgcn_mfma_f32_16x16x32_bf16(
                af[mi], bf[ni], acc[mi][ni], 0, 0, 0);
      }
#pragma unroll
      for (int mi = 0; mi < 3; ++mi)
#pragma unroll
        for (int r = 0; r < 4; ++r) {
          const int row = hl + mi * 16 + lhi * 4 + r;
#pragma unroll
          for (int ni = 0; ni < 4; ++ni) {
            const int col = ni * 16 + l15;
            const float v = acc[mi][ni][r];
            Kt[row * 64 + (((col >> 3) ^ (row & 7)) << 3) + (col & 7)] =
                f2bf(v);
            ska[mi * 4 + r] += v * v;
          }
        }
    }

    // ---- phase 2: QK^T (k=64) — reads only rows this wave wrote
    {
#pragma unroll
      for (int kk = 0; kk < 64; kk += 32) {
        s8 qa[3], ka[3];
#pragma unroll
        for (int i = 0; i < 3; ++i) {
          const int rr = hl + i * 16 + l15;
          const int cb = (((kk >> 3) + lhi) ^ (rr & 7)) << 3;
          qa[i] = *(const s8*)(&Qt[rr * 64 + cb]);
          ka[i] = *(const s8*)(&Kt[rr * 64 + cb]);
        }
#pragma unroll
        for (int mi = 0; mi < 3; ++mi)
#pragma unroll
          for (int ni = 0; ni < 3; ++ni)
            Sacc[mi][ni] = __builtin_amdgcn_mfma_f32_16x16x32_bf16(
                qa[mi], ka[ni], Sacc[mi][ni], 0, 0, 0);
      }
    }
  }

  // ---- epilogue: sumsq reduction (atomic) + S-partial store (non-atomic)
#pragma unroll
  for (int mi = 0; mi < 3; ++mi)
#pragma unroll
    for (int r = 0; r < 4; ++r) {
      float tq = sqa[mi * 4 + r], tk = ska[mi * 4 + r];
      tq += __shfl_xor(tq, 1); tq += __shfl_xor(tq, 2);
      tq += __shfl_xor(tq, 4); tq += __shfl_xor(tq, 8);
      tk += __shfl_xor(tk, 1); tk += __shfl_xor(tk, 2);
      tk += __shfl_xor(tk, 4); tk += __shfl_xor(tk, 8);
      const int row = hg * 192 + hl + mi * 16 + lhi * 4 + r;
      if (l15 == 0) {
        atomicAdd(&ssq[b * 384 + row], tq);
        atomicAdd(&ssk[b * 384 + row], tk);
      }
    }
  float* Sp = Spart + (((long)sc * 16 + b) * 8 + hg * 4 + w) * 2304;
#pragma unroll
  for (int mi = 0; mi < 3; ++mi)
#pragma unroll
    for (int ni = 0; ni < 3; ++ni)
#pragma unroll
      for (int r = 0; r < 4; ++r)
        Sp[(mi * 16 + lhi * 4 + r) * 48 + ni * 16 + l15] = Sacc[mi][ni][r];
}

// ---------------------------------------------------------------------------
// MFMA GEMM (R5 structure): 128x128 tile, 2-deep counted-vmcnt, T2 swizzle.
// Used for N (=Y@wv^T) and out (=N@xT^T).
// ---------------------------------------------------------------------------
template<int NKT, bool OUTF32, bool SWZ>
__global__ __launch_bounds__(256)
void gemm4(const short* __restrict__ A_, long Asb, int lda,
           const short* __restrict__ B_, long Bsb, int ldb,
           void* __restrict__ O_, long Osb, int ldo,
           int nbm, int nbn) {
  __shared__ __align__(16) short As[2][8192];
  __shared__ __align__(16) short Bs[2][8192];
  int f = blockIdx.x;
  if (SWZ) { const int cpx = gridDim.x >> 3; f = (f & 7) * cpx + (f >> 3); }
  const int m0 = (f % nbm) * 128;
  const int t2 = f / nbm;
  const int n0 = (t2 % nbn) * 128;
  const int bz = t2 / nbn;
  const short* Ag = A_ + (long)bz * Asb;
  const short* Bg = B_ + (long)bz * Bsb;

  const int tid = threadIdx.x, lane = tid & 63, wid = tid >> 6;
  const int l15 = lane & 15, lhi = lane >> 4;
  const int wm = (wid >> 1) * 64, wn = (wid & 1) * 64;
  const int srow = tid >> 3;
  const int skc = ((tid & 7) ^ (srow & 7)) * 8;

  f4 acc[4][4];
#pragma unroll
  for (int i = 0; i < 4; ++i)
#pragma unroll
    for (int j = 0; j < 4; ++j) acc[i][j] = (f4){0.f, 0.f, 0.f, 0.f};

#pragma unroll
  for (int it = 0; it < 4; ++it) {
    const int r = it * 32 + srow;
    gl16(Ag + (long)(m0 + r) * lda + skc, &As[0][(it * 256 + tid) * 8]);
    gl16(Bg + (long)(n0 + r) * ldb + skc, &Bs[0][(it * 256 + tid) * 8]);
  }
  if (NKT > 1) {
#pragma unroll
    for (int it = 0; it < 4; ++it) {
      const int r = it * 32 + srow;
      gl16(Ag + (long)(m0 + r) * lda + 64 + skc, &As[1][(it * 256 + tid) * 8]);
      gl16(Bg + (long)(n0 + r) * ldb + 64 + skc, &Bs[1][(it * 256 + tid) * 8]);
    }
  }

#pragma unroll
  for (int kt = 0; kt < NKT; ++kt) {
    const int cur = kt & 1;
    if (kt + 1 < NKT) asm volatile("s_waitcnt vmcnt(8)" ::: "memory");
    else              asm volatile("s_waitcnt vmcnt(0)" ::: "memory");
    __builtin_amdgcn_s_barrier();
    __builtin_amdgcn_sched_barrier(0);
#pragma unroll
    for (int kk = 0; kk < 2; ++kk) {
      const int cb = ((lhi + kk * 4) ^ (l15 & 7)) * 8;
      s8 af[4], bf[4];
#pragma unroll
      for (int i = 0; i < 4; ++i) {
        af[i] = *(const s8*)(&As[cur][(wm + i * 16 + l15) * 64 + cb]);
        bf[i] = *(const s8*)(&Bs[cur][(wn + i * 16 + l15) * 64 + cb]);
      }
#pragma unroll
      for (int mi = 0; mi < 4; ++mi)
#pragma unroll
        for (int ni = 0; ni < 4; ++ni)
          acc[mi][ni] = __builtin_amdgcn_mfma_f32_16x16x32_bf16(
              af[mi], bf[ni], acc[mi][ni], 0, 0, 0);
    }
    asm volatile("s_waitcnt lgkmcnt(0)" ::: "memory");
    __builtin_amdgcn_s_barrier();
    if (kt + 2 < NKT) {
      const int k2 = (kt + 2) * 64;
#pragma unroll
      for (int it = 0; it < 4; ++it) {
        const int r = it * 32 + srow;
        gl16(Ag + (long)(m0 + r) * lda + k2 + skc,
             &As[cur][(it * 256 + tid) * 8]);
        gl16(Bg + (long)(n0 + r) * ldb + k2 + skc,
             &Bs[cur][(it * 256 + tid) * 8]);
      }
    }
  }

#pragma unroll
  for (int mi = 0; mi < 4; ++mi)
#pragma unroll
    for (int r = 0; r < 4; ++r) {
      const int grow = m0 + wm + mi * 16 + lhi * 4 + r;
#pragma unroll
      for (int ni = 0; ni < 4; ++ni) {
        const int col = n0 + wn + ni * 16 + l15;
        const float v = acc[mi][ni][r];
        if (OUTF32)
          ((float*)O_)[(long)bz * Osb + (long)grow * ldo + col] = v;
        else
          ((short*)O_)[(long)bz * Osb + (long)grow * ldo + col] = f2bf(v);
      }
    }
}

// ---------------------------------------------------------------------------
// Combined prep: roles 0-5: x -> xT[4096][384]; 6-8: q -> qT; role 9:
// weight casts (wk, wvT transposed, wq, wp) + zero ssq/ssk.
// ---------------------------------------------------------------------------
__global__ __launch_bounds__(256)
void prep_k(const float* __restrict__ x, const float* __restrict__ q,
            const float* __restrict__ wkv, const float* __restrict__ wq,
            const float* __restrict__ wp, short* __restrict__ xT,
            short* __restrict__ qT, short* __restrict__ wkb,
            short* __restrict__ wvT, short* __restrict__ wqb,
            short* __restrict__ wpb, float* __restrict__ ssqk) {
  const int role = blockIdx.x;
  if (role == 9) {
    const int g = (blockIdx.z * 64 + blockIdx.y) * 256 + threadIdx.x; // <262144
    if (g < 12288) ssqk[g] = 0.f;
    for (int i = g; i < 516096; i += 262144) {
      if (i < 147456) {
        wkb[i] = f2bf(wkv[i]);
      } else if (i < 294912) {
        const int t = i - 147456;
        wvT[t] = f2bf(wkv[(384 + (t % 384)) * 384 + t / 384]);
      } else if (i < 368640) {
        wqb[i - 294912] = f2bf(wq[i - 294912]);
      } else {
        wpb[i - 368640] = f2bf(wp[i - 368640]);
      }
    }
    return;
  }
  __shared__ float Ls[64][65];
  const bool isQ = role >= 6;
  const int C = isQ ? 192 : 384;
  const int c0 = (isQ ? role - 6 : role) * 64;
  const int s0 = blockIdx.y * 64;
  const float* src = (isQ ? q : x) + (long)blockIdx.z * C * 4096;
  short* dst = (isQ ? qT : xT) + (long)blockIdx.z * 4096 * C;
  const int tid = threadIdx.x;
  const int rr = tid >> 4, cq = (tid & 15) * 4;
#pragma unroll
  for (int it = 0; it < 4; ++it) {
    const int r = it * 16 + rr;
    f4 v = *(const f4*)(src + (long)(c0 + r) * 4096 + s0 + cq);
    Ls[r][cq + 0] = v.x; Ls[r][cq + 1] = v.y;
    Ls[r][cq + 2] = v.z; Ls[r][cq + 3] = v.w;
  }
  __syncthreads();
#pragma unroll
  for (int it = 0; it < 4; ++it) {
    const int sr = it * 16 + rr;
    s4 o;
#pragma unroll
    for (int j = 0; j < 4; ++j) o[j] = f2bf(Ls[cq + j][sr]);
    *(s4*)(&dst[(long)(s0 + sr) * C + c0 + cq]) = o;
  }
}

// ---------------------------------------------------------------------------
// softmax + Y fusion per (b,h): reduce 16 z-partials, logits, row softmax ->
// P^T in LDS (c padded 48->64 with zeros); then Y[:,h*48+d] = wp[:,hblk]@P
// via MFMA. Head h is the only writer of Y's column block.
// ---------------------------------------------------------------------------
__global__ __launch_bounds__(256)
void smY_k(const float* __restrict__ Spart, const float* __restrict__ ssq,
           const float* __restrict__ ssk, const float* __restrict__ temp,
           const short* __restrict__ wpb, short* __restrict__ Yb) {
  const int b = blockIdx.x, h = blockIdx.y, tid = threadIdx.x;
  __shared__ float L[2304];
  __shared__ float rq[48], rk[48], mrow[48], irow[48];
  __shared__ __align__(16) short PTl[48 * 72];   // [d][c] padded ld=72
  if (tid < 48) {
    rq[tid] = 1.f / fmaxf(sqrtf(ssq[b * 384 + h * 48 + tid]), 1e-12f);
    rk[tid] = 1.f / fmaxf(sqrtf(ssk[b * 384 + h * 48 + tid]), 1e-12f);
  }
  __syncthreads();
  const float tp = temp[h];
  for (int i = tid; i < 2304; i += 256) {
    float v = 0.f;
#pragma unroll
    for (int z = 0; z < 16; ++z)
      v += Spart[(((long)z * 16 + b) * 8 + h) * 2304 + i];
    const int c = i / 48, d = i % 48;
    L[i] = v * rq[c] * rk[d] * tp;
  }
  __syncthreads();
  if (tid < 48) {
    float m = -1e30f;
    for (int d = 0; d < 48; ++d) m = fmaxf(m, L[tid * 48 + d]);
    float s = 0.f;
    for (int d = 0; d < 48; ++d) s += __expf(L[tid * 48 + d] - m);
    mrow[tid] = m;
    irow[tid] = 1.f / s;
  }
  __syncthreads();
  for (int i = tid; i < 48 * 72; i += 256) {
    const int d = i / 72, c = i % 72;
    float p = 0.f;
    if (c < 48) p = __expf(L[c * 48 + d] - mrow[c]) * irow[c];
    PTl[i] = f2bf(p);
  }
  __syncthreads();
  const int lane = tid & 63, w = tid >> 6;
  const int l15 = lane & 15, lhi = lane >> 4;
  f4 acc[6][3];
#pragma unroll
  for (int i = 0; i < 6; ++i)
#pragma unroll
    for (int j = 0; j < 3; ++j) acc[i][j] = (f4){0.f, 0.f, 0.f, 0.f};
#pragma unroll
  for (int kk = 0; kk < 2; ++kk) {
    s8 bf[3];
#pragma unroll
    for (int ni = 0; ni < 3; ++ni)
      bf[ni] = *(const s8*)(&PTl[(ni * 16 + l15) * 72 + kk * 32 + lhi * 8]);
#pragma unroll
    for (int mi = 0; mi < 6; ++mi) {
      const int row = w * 96 + mi * 16 + l15;
      s8 af = *(const s8*)(wpb + (long)row * 384 + h * 48 + kk * 32 + lhi * 8);
#pragma unroll
      for (int ni = 0; ni < 3; ++ni)
        acc[mi][ni] = __builtin_amdgcn_mfma_f32_16x16x32_bf16(
            af, bf[ni], acc[mi][ni], 0, 0, 0);
    }
  }
#pragma unroll
  for (int mi = 0; mi < 6; ++mi)
#pragma unroll
    for (int r = 0; r < 4; ++r) {
      const int row = w * 96 + mi * 16 + lhi * 4 + r;
#pragma unroll
      for (int ni = 0; ni < 3; ++ni) {
        const int d = ni * 16 + l15;
        Yb[((long)b * 384 + row) * 384 + h * 48 + d] = f2bf(acc[mi][ni][r]);
      }
    }
}

extern "C" void kernel_launch(void* const* d_in, const int* in_sizes, int n_in,
                              void* d_out, int out_size, void* d_ws, size_t ws_size,
                              hipStream_t stream) {
  const float* x = (const float*)d_in[0];
  const float* query = (const float*)d_in[1];
  const float* w_kv = (const float*)d_in[2];
  const float* w_q = (const float*)d_in[3];
  const float* w_proj = (const float*)d_in[4];
  const float* temp = (const float*)d_in[5];

  // workspace carve (~105 MB), all offsets 16B-aligned
  char* w = (char*)d_ws;
  short* xT   = (short*)(w + 0);            // [16][4096][384] bf16
  short* qT   = (short*)(w + 50331648);     // [16][4096][192] bf16
  float* Spart= (float*)(w + 75497472);     // [16][16][8][2304] f32
  short* Yb   = (short*)(w + 94371840);     // [16][384][384] bf16
  short* Nbb  = (short*)(w + 99090432);     // [16][384][384] bf16
  float* ssq  = (float*)(w + 103809024);    // [16][384] f32
  float* ssk  = (float*)(w + 103833600);    // [16][384] f32
  short* wkb  = (short*)(w + 103858176);
  short* wvT  = (short*)(w + 104153088);
  short* wqb  = (short*)(w + 104448000);
  short* wpb  = (short*)(w + 104595456);
  float* out  = (float*)d_out;

  // transposes + casts + weight prep + sumsq zeroing (one launch)
  prep_k<<<dim3(10, 64, 16), 256, 0, stream>>>(
      x, query, w_kv, w_q, w_proj, xT, qT, wkb, wvT, wqb, wpb, ssq);
  // fused K/Q GEMM + QK^T partials (+ sumsq), barrier-free, 2 blocks/CU
  kqs_k<<<512, 256, 0, stream>>>(xT, qT, wkb, wqb, Spart, ssq, ssk);
  // softmax + Y = wp @ P  (per-head column block)
  smY_k<<<dim3(16, 8), 256, 0, stream>>>(Spart, ssq, ssk, temp, wpb, Yb);
  // N[o][j] = sum_d Y[o,d] wvT[j,d]
  gemm4<6, false, false><<<144, 256, 0, stream>>>(
      Yb, 147456, 384, wvT, 0, 384, Nbb, 147456, 384, 3, 3);
  // out[o][s] = sum_j N[o,j] xT[s,j]  (f32)
  gemm4<6, true, true><<<1536, 256, 0, stream>>>(
      Nbb, 147456, 384, xT, 1572864, 384, out, 1572864, 4096, 3, 32);
}

// Round 13
// 250.247 us; speedup vs baseline: 1.2549x; 1.2549x over previous
//
#include <hip/hip_runtime.h>
#include <hip/hip_bf16.h>

typedef float f4 __attribute__((ext_vector_type(4)));
typedef short s8 __attribute__((ext_vector_type(8)));
typedef short s4 __attribute__((ext_vector_type(4)));

__device__ __forceinline__ short f2bf(float f) {
  union { float f; unsigned u; } v; v.f = f;
  unsigned r = v.u + 0x7fffu + ((v.u >> 16) & 1u);
  return (short)(r >> 16);
}
// async global->LDS, 16B/lane; LDS dest = wave-uniform base + lane*16 (linear)
__device__ __forceinline__ void gl16(const short* g, short* l) {
  __builtin_amdgcn_global_load_lds(
      (const __attribute__((address_space(1))) unsigned*)g,
      (__attribute__((address_space(3))) unsigned*)l, 16, 0, 0);
}

// ---------------------------------------------------------------------------
// FUSED K/Q-GEMM + QK^T v4 — 8-wave block (2 waves/SIMD latency co-cover).
//  grid = 256 (1 block/CU, 512 thr), block = (b, sc in [0,16)) -> 256-col
//  chunk, 4 slices x 64 cols. Wave w in [0,8) = head w (both head-groups).
//  Per-wave phase structure IDENTICAL to the proven R8/R11 kernel.
//  LDS 147.5 KB: Qt[384][64], Kt[384][64], Bx[64][384]; Bq[64][192]
//  ALIASES Kt rows 0-191 (Bq dead after post-1Q barrier; 1K overwrites it;
//  restage gated by post-phase2 barrier). 3 barriers/slice.
//  vmcnt discipline: stage Bq(t+1) BEFORE Bx(t+1) (both post-phase2) so
//  slice-top vmcnt(6) retires exactly the 3 Bq gl16s (FIFO).
// ---------------------------------------------------------------------------
__global__ __launch_bounds__(512, 2)
void kqs_k(const short* __restrict__ xT, const short* __restrict__ qT,
           const short* __restrict__ wkb, const short* __restrict__ wqb,
           float* __restrict__ Spart, float* __restrict__ ssq,
           float* __restrict__ ssk) {
  __shared__ __align__(16) short Qt[384 * 64];   // 48 KB
  __shared__ __align__(16) short Kt[384 * 64];   // 48 KB; rows 0-191 = Bq
  __shared__ __align__(16) short Bx[64 * 384];   // 48 KB
  short* Bq = Kt;                                // [64][192] staging alias
  const int orig = blockIdx.x;
  const int idx = (orig & 7) * 32 + (orig >> 3); // XCD chunking, [0,256)
  const int b = idx >> 4, sc = idx & 15;
  const int tid = threadIdx.x, lane = tid & 63, w = tid >> 6;  // w in [0,8)
  const int l15 = lane & 15, lhi = lane >> 4;
  const int hl = w * 48;                         // global Q/K row base

  const short* qTb = qT + ((long)b * 4096 + sc * 256) * 192;
  const short* xTb = xT + ((long)b * 4096 + sc * 256) * 384;

  f4 Sacc[3][3];
#pragma unroll
  for (int i = 0; i < 3; ++i)
#pragma unroll
    for (int j = 0; j < 3; ++j) Sacc[i][j] = (f4){0.f, 0.f, 0.f, 0.f};
  float sqa[12], ska[12];
#pragma unroll
  for (int i = 0; i < 12; ++i) { sqa[i] = 0.f; ska[i] = 0.f; }

  // prologue: stage slice 0 — Bq (3 gl16/thread) FIRST, then Bx (6)
#pragma unroll
  for (int i = 0; i < 3; ++i) {
    const int q = i * 512 + tid, row = q / 24, c = q % 24;
    gl16(qTb + row * 192 + ((c ^ (row & 7)) * 8), &Bq[q * 8]);
  }
#pragma unroll
  for (int i = 0; i < 6; ++i) {
    const int q = i * 512 + tid, row = q / 48, c = q % 48;
    gl16(xTb + row * 384 + ((c ^ (row & 7)) * 8), &Bx[q * 8]);
  }

#pragma unroll 1
  for (int t = 0; t < 4; ++t) {
    asm volatile("s_waitcnt vmcnt(6)" ::: "memory");   // Bq(t) landed
    __builtin_amdgcn_s_barrier();
    __builtin_amdgcn_sched_barrier(0);

    // ---- phase 1Q: Qt[rows hl..hl+47][64] = wq @ Bq (K=192)
    {
      f4 acc[3][4];
#pragma unroll
      for (int i = 0; i < 3; ++i)
#pragma unroll
        for (int j = 0; j < 4; ++j) acc[i][j] = (f4){0.f, 0.f, 0.f, 0.f};
#pragma unroll 2
      for (int kk = 0; kk < 192; kk += 32) {
        s8 af[3], bf[4];
#pragma unroll
        for (int mi = 0; mi < 3; ++mi)
          af[mi] = *(const s8*)(wqb +
              (long)(hl + mi * 16 + l15) * 192 + kk + lhi * 8);
#pragma unroll
        for (int ni = 0; ni < 4; ++ni) {
          const int s_ = ni * 16 + l15;
          bf[ni] = *(const s8*)(&Bq[s_ * 192 +
                                    ((((kk >> 3) + lhi) ^ (s_ & 7)) << 3)]);
        }
#pragma unroll
        for (int mi = 0; mi < 3; ++mi)
#pragma unroll
          for (int ni = 0; ni < 4; ++ni)
            acc[mi][ni] = __builtin_amdgcn_mfma_f32_16x16x32_bf16(
                af[mi], bf[ni], acc[mi][ni], 0, 0, 0);
      }
#pragma unroll
      for (int mi = 0; mi < 3; ++mi)
#pragma unroll
        for (int r = 0; r < 4; ++r) {
          const int row = hl + mi * 16 + lhi * 4 + r;
#pragma unroll
          for (int ni = 0; ni < 4; ++ni) {
            const int col = ni * 16 + l15;
            const float v = acc[mi][ni][r];
            Qt[row * 64 + (((col >> 3) ^ (row & 7)) << 3) + (col & 7)] =
                f2bf(v);
            sqa[mi * 4 + r] += v * v;
          }
        }
    }

    // Bx(t) landed; ALL waves' Bq reads drained (lgkm0) -> Kt alias writable
    asm volatile("s_waitcnt vmcnt(0) lgkmcnt(0)" ::: "memory");
    __builtin_amdgcn_s_barrier();
    __builtin_amdgcn_sched_barrier(0);

    // ---- phase 1K: Kt[rows hl..hl+47][64] = wk @ Bx (K=384)
    {
      f4 acc[3][4];
#pragma unroll
      for (int i = 0; i < 3; ++i)
#pragma unroll
        for (int j = 0; j < 4; ++j) acc[i][j] = (f4){0.f, 0.f, 0.f, 0.f};
#pragma unroll 2
      for (int kk = 0; kk < 384; kk += 32) {
        s8 af[3], bf[4];
#pragma unroll
        for (int mi = 0; mi < 3; ++mi)
          af[mi] = *(const s8*)(wkb +
              (long)(hl + mi * 16 + l15) * 384 + kk + lhi * 8);
#pragma unroll
        for (int ni = 0; ni < 4; ++ni) {
          const int s_ = ni * 16 + l15;
          bf[ni] = *(const s8*)(&Bx[s_ * 384 +
                                    ((((kk >> 3) + lhi) ^ (s_ & 7)) << 3)]);
        }
#pragma unroll
        for (int mi = 0; mi < 3; ++mi)
#pragma unroll
          for (int ni = 0; ni < 4; ++ni)
            acc[mi][ni] = __builtin_amdgcn_mfma_f32_16x16x32_bf16(
                af[mi], bf[ni], acc[mi][ni], 0, 0, 0);
      }
#pragma unroll
      for (int mi = 0; mi < 3; ++mi)
#pragma unroll
        for (int r = 0; r < 4; ++r) {
          const int row = hl + mi * 16 + lhi * 4 + r;
#pragma unroll
          for (int ni = 0; ni < 4; ++ni) {
            const int col = ni * 16 + l15;
            const float v = acc[mi][ni][r];
            Kt[row * 64 + (((col >> 3) ^ (row & 7)) << 3) + (col & 7)] =
                f2bf(v);
            ska[mi * 4 + r] += v * v;
          }
        }
    }

    // ---- phase 2: QK^T (k=64) — own rows only (same-wave LDS ordering)
    {
#pragma unroll
      for (int kk = 0; kk < 64; kk += 32) {
        s8 qa[3], ka[3];
#pragma unroll
        for (int i = 0; i < 3; ++i) {
          const int rr = hl + i * 16 + l15;
          const int cb = (((kk >> 3) + lhi) ^ (rr & 7)) << 3;
          qa[i] = *(const s8*)(&Qt[rr * 64 + cb]);
          ka[i] = *(const s8*)(&Kt[rr * 64 + cb]);
        }
#pragma unroll
        for (int mi = 0; mi < 3; ++mi)
#pragma unroll
          for (int ni = 0; ni < 3; ++ni)
            Sacc[mi][ni] = __builtin_amdgcn_mfma_f32_16x16x32_bf16(
                qa[mi], ka[ni], Sacc[mi][ni], 0, 0, 0);
      }
    }

    // all phase2 LDS reads done -> alias region + Bx free for restage
    asm volatile("s_waitcnt lgkmcnt(0)" ::: "memory");
    __builtin_amdgcn_s_barrier();
    if (t + 1 < 4) {
      const long so = (long)(t + 1) * 64;
#pragma unroll
      for (int i = 0; i < 3; ++i) {                 // Bq first (oldest)
        const int q = i * 512 + tid, row = q / 24, c = q % 24;
        gl16(qTb + (so + row) * 192 + ((c ^ (row & 7)) * 8), &Bq[q * 8]);
      }
#pragma unroll
      for (int i = 0; i < 6; ++i) {
        const int q = i * 512 + tid, row = q / 48, c = q % 48;
        gl16(xTb + (so + row) * 384 + ((c ^ (row & 7)) * 8), &Bx[q * 8]);
      }
    }
  }

  // ---- epilogue: sumsq reduction (atomic) + S-partial store (non-atomic)
#pragma unroll
  for (int mi = 0; mi < 3; ++mi)
#pragma unroll
    for (int r = 0; r < 4; ++r) {
      float tq = sqa[mi * 4 + r], tk = ska[mi * 4 + r];
      tq += __shfl_xor(tq, 1); tq += __shfl_xor(tq, 2);
      tq += __shfl_xor(tq, 4); tq += __shfl_xor(tq, 8);
      tk += __shfl_xor(tk, 1); tk += __shfl_xor(tk, 2);
      tk += __shfl_xor(tk, 4); tk += __shfl_xor(tk, 8);
      const int row = hl + mi * 16 + lhi * 4 + r;
      if (l15 == 0) {
        atomicAdd(&ssq[b * 384 + row], tq);
        atomicAdd(&ssk[b * 384 + row], tk);
      }
    }
  float* Sp = Spart + (((long)sc * 16 + b) * 8 + w) * 2304;
#pragma unroll
  for (int mi = 0; mi < 3; ++mi)
#pragma unroll
    for (int ni = 0; ni < 3; ++ni)
#pragma unroll
      for (int r = 0; r < 4; ++r)
        Sp[(mi * 16 + lhi * 4 + r) * 48 + ni * 16 + l15] = Sacc[mi][ni][r];
}

// ---------------------------------------------------------------------------
// MFMA GEMM (R5 structure): 128x128 tile, 2-deep counted-vmcnt, T2 swizzle.
// Used for N (=Y@wv^T) and out (=N@xT^T).
// ---------------------------------------------------------------------------
template<int NKT, bool OUTF32, bool SWZ>
__global__ __launch_bounds__(256)
void gemm4(const short* __restrict__ A_, long Asb, int lda,
           const short* __restrict__ B_, long Bsb, int ldb,
           void* __restrict__ O_, long Osb, int ldo,
           int nbm, int nbn) {
  __shared__ __align__(16) short As[2][8192];
  __shared__ __align__(16) short Bs[2][8192];
  int f = blockIdx.x;
  if (SWZ) { const int cpx = gridDim.x >> 3; f = (f & 7) * cpx + (f >> 3); }
  const int m0 = (f % nbm) * 128;
  const int t2 = f / nbm;
  const int n0 = (t2 % nbn) * 128;
  const int bz = t2 / nbn;
  const short* Ag = A_ + (long)bz * Asb;
  const short* Bg = B_ + (long)bz * Bsb;

  const int tid = threadIdx.x, lane = tid & 63, wid = tid >> 6;
  const int l15 = lane & 15, lhi = lane >> 4;
  const int wm = (wid >> 1) * 64, wn = (wid & 1) * 64;
  const int srow = tid >> 3;
  const int skc = ((tid & 7) ^ (srow & 7)) * 8;

  f4 acc[4][4];
#pragma unroll
  for (int i = 0; i < 4; ++i)
#pragma unroll
    for (int j = 0; j < 4; ++j) acc[i][j] = (f4){0.f, 0.f, 0.f, 0.f};

#pragma unroll
  for (int it = 0; it < 4; ++it) {
    const int r = it * 32 + srow;
    gl16(Ag + (long)(m0 + r) * lda + skc, &As[0][(it * 256 + tid) * 8]);
    gl16(Bg + (long)(n0 + r) * ldb + skc, &Bs[0][(it * 256 + tid) * 8]);
  }
  if (NKT > 1) {
#pragma unroll
    for (int it = 0; it < 4; ++it) {
      const int r = it * 32 + srow;
      gl16(Ag + (long)(m0 + r) * lda + 64 + skc, &As[1][(it * 256 + tid) * 8]);
      gl16(Bg + (long)(n0 + r) * ldb + 64 + skc, &Bs[1][(it * 256 + tid) * 8]);
    }
  }

#pragma unroll
  for (int kt = 0; kt < NKT; ++kt) {
    const int cur = kt & 1;
    if (kt + 1 < NKT) asm volatile("s_waitcnt vmcnt(8)" ::: "memory");
    else              asm volatile("s_waitcnt vmcnt(0)" ::: "memory");
    __builtin_amdgcn_s_barrier();
    __builtin_amdgcn_sched_barrier(0);
#pragma unroll
    for (int kk = 0; kk < 2; ++kk) {
      const int cb = ((lhi + kk * 4) ^ (l15 & 7)) * 8;
      s8 af[4], bf[4];
#pragma unroll
      for (int i = 0; i < 4; ++i) {
        af[i] = *(const s8*)(&As[cur][(wm + i * 16 + l15) * 64 + cb]);
        bf[i] = *(const s8*)(&Bs[cur][(wn + i * 16 + l15) * 64 + cb]);
      }
#pragma unroll
      for (int mi = 0; mi < 4; ++mi)
#pragma unroll
        for (int ni = 0; ni < 4; ++ni)
          acc[mi][ni] = __builtin_amdgcn_mfma_f32_16x16x32_bf16(
              af[mi], bf[ni], acc[mi][ni], 0, 0, 0);
    }
    asm volatile("s_waitcnt lgkmcnt(0)" ::: "memory");
    __builtin_amdgcn_s_barrier();
    if (kt + 2 < NKT) {
      const int k2 = (kt + 2) * 64;
#pragma unroll
      for (int it = 0; it < 4; ++it) {
        const int r = it * 32 + srow;
        gl16(Ag + (long)(m0 + r) * lda + k2 + skc,
             &As[cur][(it * 256 + tid) * 8]);
        gl16(Bg + (long)(n0 + r) * ldb + k2 + skc,
             &Bs[cur][(it * 256 + tid) * 8]);
      }
    }
  }

#pragma unroll
  for (int mi = 0; mi < 4; ++mi)
#pragma unroll
    for (int r = 0; r < 4; ++r) {
      const int grow = m0 + wm + mi * 16 + lhi * 4 + r;
#pragma unroll
      for (int ni = 0; ni < 4; ++ni) {
        const int col = n0 + wn + ni * 16 + l15;
        const float v = acc[mi][ni][r];
        if (OUTF32)
          ((float*)O_)[(long)bz * Osb + (long)grow * ldo + col] = v;
        else
          ((short*)O_)[(long)bz * Osb + (long)grow * ldo + col] = f2bf(v);
      }
    }
}

// ---------------------------------------------------------------------------
// Combined prep: roles 0-5: x -> xT[4096][384]; 6-8: q -> qT; role 9:
// weight casts (wk, wvT transposed, wq, wp) + zero ssq/ssk.
// ---------------------------------------------------------------------------
__global__ __launch_bounds__(256)
void prep_k(const float* __restrict__ x, const float* __restrict__ q,
            const float* __restrict__ wkv, const float* __restrict__ wq,
            const float* __restrict__ wp, short* __restrict__ xT,
            short* __restrict__ qT, short* __restrict__ wkb,
            short* __restrict__ wvT, short* __restrict__ wqb,
            short* __restrict__ wpb, float* __restrict__ ssqk) {
  const int role = blockIdx.x;
  if (role == 9) {
    const int g = (blockIdx.z * 64 + blockIdx.y) * 256 + threadIdx.x; // <262144
    if (g < 12288) ssqk[g] = 0.f;
    for (int i = g; i < 516096; i += 262144) {
      if (i < 147456) {
        wkb[i] = f2bf(wkv[i]);
      } else if (i < 294912) {
        const int t = i - 147456;
        wvT[t] = f2bf(wkv[(384 + (t % 384)) * 384 + t / 384]);
      } else if (i < 368640) {
        wqb[i - 294912] = f2bf(wq[i - 294912]);
      } else {
        wpb[i - 368640] = f2bf(wp[i - 368640]);
      }
    }
    return;
  }
  __shared__ float Ls[64][65];
  const bool isQ = role >= 6;
  const int C = isQ ? 192 : 384;
  const int c0 = (isQ ? role - 6 : role) * 64;
  const int s0 = blockIdx.y * 64;
  const float* src = (isQ ? q : x) + (long)blockIdx.z * C * 4096;
  short* dst = (isQ ? qT : xT) + (long)blockIdx.z * 4096 * C;
  const int tid = threadIdx.x;
  const int rr = tid >> 4, cq = (tid & 15) * 4;
#pragma unroll
  for (int it = 0; it < 4; ++it) {
    const int r = it * 16 + rr;
    f4 v = *(const f4*)(src + (long)(c0 + r) * 4096 + s0 + cq);
    Ls[r][cq + 0] = v.x; Ls[r][cq + 1] = v.y;
    Ls[r][cq + 2] = v.z; Ls[r][cq + 3] = v.w;
  }
  __syncthreads();
#pragma unroll
  for (int it = 0; it < 4; ++it) {
    const int sr = it * 16 + rr;
    s4 o;
#pragma unroll
    for (int j = 0; j < 4; ++j) o[j] = f2bf(Ls[cq + j][sr]);
    *(s4*)(&dst[(long)(s0 + sr) * C + c0 + cq]) = o;
  }
}

// ---------------------------------------------------------------------------
// softmax + Y fusion per (b,h): reduce 16 z-partials, logits, row softmax ->
// P^T in LDS (c padded 48->64 with zeros); then Y[:,h*48+d] = wp[:,hblk]@P
// via MFMA. Head h is the only writer of Y's column block.
// ---------------------------------------------------------------------------
__global__ __launch_bounds__(256)
void smY_k(const float* __restrict__ Spart, const float* __restrict__ ssq,
           const float* __restrict__ ssk, const float* __restrict__ temp,
           const short* __restrict__ wpb, short* __restrict__ Yb) {
  const int b = blockIdx.x, h = blockIdx.y, tid = threadIdx.x;
  __shared__ float L[2304];
  __shared__ float rq[48], rk[48], mrow[48], irow[48];
  __shared__ __align__(16) short PTl[48 * 72];   // [d][c] padded ld=72
  if (tid < 48) {
    rq[tid] = 1.f / fmaxf(sqrtf(ssq[b * 384 + h * 48 + tid]), 1e-12f);
    rk[tid] = 1.f / fmaxf(sqrtf(ssk[b * 384 + h * 48 + tid]), 1e-12f);
  }
  __syncthreads();
  const float tp = temp[h];
  for (int i = tid; i < 2304; i += 256) {
    float v = 0.f;
#pragma unroll
    for (int z = 0; z < 16; ++z)
      v += Spart[(((long)z * 16 + b) * 8 + h) * 2304 + i];
    const int c = i / 48, d = i % 48;
    L[i] = v * rq[c] * rk[d] * tp;
  }
  __syncthreads();
  if (tid < 48) {
    float m = -1e30f;
    for (int d = 0; d < 48; ++d) m = fmaxf(m, L[tid * 48 + d]);
    float s = 0.f;
    for (int d = 0; d < 48; ++d) s += __expf(L[tid * 48 + d] - m);
    mrow[tid] = m;
    irow[tid] = 1.f / s;
  }
  __syncthreads();
  for (int i = tid; i < 48 * 72; i += 256) {
    const int d = i / 72, c = i % 72;
    float p = 0.f;
    if (c < 48) p = __expf(L[c * 48 + d] - mrow[c]) * irow[c];
    PTl[i] = f2bf(p);
  }
  __syncthreads();
  const int lane = tid & 63, w = tid >> 6;
  const int l15 = lane & 15, lhi = lane >> 4;
  f4 acc[6][3];
#pragma unroll
  for (int i = 0; i < 6; ++i)
#pragma unroll
    for (int j = 0; j < 3; ++j) acc[i][j] = (f4){0.f, 0.f, 0.f, 0.f};
#pragma unroll
  for (int kk = 0; kk < 2; ++kk) {
    s8 bf[3];
#pragma unroll
    for (int ni = 0; ni < 3; ++ni)
      bf[ni] = *(const s8*)(&PTl[(ni * 16 + l15) * 72 + kk * 32 + lhi * 8]);
#pragma unroll
    for (int mi = 0; mi < 6; ++mi) {
      const int row = w * 96 + mi * 16 + l15;
      s8 af = *(const s8*)(wpb + (long)row * 384 + h * 48 + kk * 32 + lhi * 8);
#pragma unroll
      for (int ni = 0; ni < 3; ++ni)
        acc[mi][ni] = __builtin_amdgcn_mfma_f32_16x16x32_bf16(
            af, bf[ni], acc[mi][ni], 0, 0, 0);
    }
  }
#pragma unroll
  for (int mi = 0; mi < 6; ++mi)
#pragma unroll
    for (int r = 0; r < 4; ++r) {
      const int row = w * 96 + mi * 16 + lhi * 4 + r;
#pragma unroll
      for (int ni = 0; ni < 3; ++ni) {
        const int d = ni * 16 + l15;
        Yb[((long)b * 384 + row) * 384 + h * 48 + d] = f2bf(acc[mi][ni][r]);
      }
    }
}

extern "C" void kernel_launch(void* const* d_in, const int* in_sizes, int n_in,
                              void* d_out, int out_size, void* d_ws, size_t ws_size,
                              hipStream_t stream) {
  const float* x = (const float*)d_in[0];
  const float* query = (const float*)d_in[1];
  const float* w_kv = (const float*)d_in[2];
  const float* w_q = (const float*)d_in[3];
  const float* w_proj = (const float*)d_in[4];
  const float* temp = (const float*)d_in[5];

  // workspace carve (~105 MB), all offsets 16B-aligned
  char* w = (char*)d_ws;
  short* xT   = (short*)(w + 0);            // [16][4096][384] bf16
  short* qT   = (short*)(w + 50331648);     // [16][4096][192] bf16
  float* Spart= (float*)(w + 75497472);     // [16][16][8][2304] f32
  short* Yb   = (short*)(w + 94371840);     // [16][384][384] bf16
  short* Nbb  = (short*)(w + 99090432);     // [16][384][384] bf16
  float* ssq  = (float*)(w + 103809024);    // [16][384] f32
  float* ssk  = (float*)(w + 103833600);    // [16][384] f32
  short* wkb  = (short*)(w + 103858176);
  short* wvT  = (short*)(w + 104153088);
  short* wqb  = (short*)(w + 104448000);
  short* wpb  = (short*)(w + 104595456);
  float* out  = (float*)d_out;

  // transposes + casts + weight prep + sumsq zeroing (one launch)
  prep_k<<<dim3(10, 64, 16), 256, 0, stream>>>(
      x, query, w_kv, w_q, w_proj, xT, qT, wkb, wvT, wqb, wpb, ssq);
  // fused K/Q GEMM + QK^T partials (+ sumsq), 8-wave blocks, 1 block/CU
  kqs_k<<<256, 512, 0, stream>>>(xT, qT, wkb, wqb, Spart, ssq, ssk);
  // softmax + Y = wp @ P  (per-head column block)
  smY_k<<<dim3(16, 8), 256, 0, stream>>>(Spart, ssq, ssk, temp, wpb, Yb);
  // N[o][j] = sum_d Y[o,d] wvT[j,d]
  gemm4<6, false, false><<<144, 256, 0, stream>>>(
      Yb, 147456, 384, wvT, 0, 384, Nbb, 147456, 384, 3, 3);
  // out[o][s] = sum_j N[o,j] xT[s,j]  (f32)
  gemm4<6, true, true><<<1536, 256, 0, stream>>>(
      Nbb, 147456, 384, xT, 1572864, 384, out, 1572864, 4096, 3, 32);
}

// Round 14
// 189.791 us; speedup vs baseline: 1.6546x; 1.3185x over previous
//
#include <hip/hip_runtime.h>
#include <hip/hip_bf16.h>

typedef float f4 __attribute__((ext_vector_type(4)));
typedef short s8 __attribute__((ext_vector_type(8)));
typedef short s4 __attribute__((ext_vector_type(4)));

__device__ __forceinline__ short f2bf(float f) {
  union { float f; unsigned u; } v; v.f = f;
  unsigned r = v.u + 0x7fffu + ((v.u >> 16) & 1u);
  return (short)(r >> 16);
}
// async global->LDS, 16B/lane; LDS dest = wave-uniform base + lane*16 (linear)
__device__ __forceinline__ void gl16(const short* g, short* l) {
  __builtin_amdgcn_global_load_lds(
      (const __attribute__((address_space(1))) unsigned*)g,
      (__attribute__((address_space(3))) unsigned*)l, 16, 0, 0);
}

// ---------------------------------------------------------------------------
// FUSED K-GEMM + Q-GEMM + QK^T (R8 geometry — measured optimum: 97.7-98.8us).
//  grid = 256 (1 block/CU), block = (b, sc in [0,8), hg); 8 slices x 64 cols.
//  LDS 120 KB: Bq[64][192], Bx[64][384] (XOR-swizzled via pre-swizzled
//  global source, rule-21), Qt/Kt[192][64] (XOR-swizzled write+read).
//  Register S-acc (48x48/wave), no S atomics; sumsq in regs, one atomic
//  set per block. N=64 slices keep the weight-load:MFMA ratio low.
//  [R9-R13 exploration: narrower slices (-21us), no-LDS B (-123us), 8-wave
//  blocks (-51us) all regressed — this configuration is the plateau.]
// ---------------------------------------------------------------------------
__global__ __launch_bounds__(256, 1)
void kqs_k(const short* __restrict__ xT, const short* __restrict__ qT,
           const short* __restrict__ wkb, const short* __restrict__ wqb,
           float* __restrict__ Spart, float* __restrict__ ssq,
           float* __restrict__ ssk) {
  __shared__ __align__(16) short Bq[64 * 192];   // 24 KB
  __shared__ __align__(16) short Bx[64 * 384];   // 48 KB
  __shared__ __align__(16) short Qt[192 * 64];   // 24 KB
  __shared__ __align__(16) short Kt[192 * 64];   // 24 KB
  const int orig = blockIdx.x;
  const int xcd = orig & 7, ix = orig >> 3;      // ix in [0,32)
  const int pair = xcd * 16 + (ix >> 1);         // [0,128): (b, sc)
  const int hg = ix & 1;
  const int b = pair >> 3, sc = pair & 7;
  const int tid = threadIdx.x, lane = tid & 63, w = tid >> 6;
  const int l15 = lane & 15, lhi = lane >> 4;

  const short* qTb = qT + ((long)b * 4096 + sc * 512) * 192;
  const short* xTb = xT + ((long)b * 4096 + sc * 512) * 384;

  f4 Sacc[3][3];
#pragma unroll
  for (int i = 0; i < 3; ++i)
#pragma unroll
    for (int j = 0; j < 3; ++j) Sacc[i][j] = (f4){0.f, 0.f, 0.f, 0.f};
  float sqa[12], ska[12];
#pragma unroll
  for (int i = 0; i < 12; ++i) { sqa[i] = 0.f; ska[i] = 0.f; }

  // prologue: stage slice 0 (Bq: 6 gl16/thread, then Bx: 12)
#pragma unroll
  for (int i = 0; i < 6; ++i) {
    const int q = i * 256 + tid, row = q / 24, c = q % 24;
    gl16(qTb + row * 192 + ((c ^ (row & 7)) * 8), &Bq[q * 8]);
  }
#pragma unroll
  for (int i = 0; i < 12; ++i) {
    const int q = i * 256 + tid, row = q / 48, c = q % 48;
    gl16(xTb + row * 384 + ((c ^ (row & 7)) * 8), &Bx[q * 8]);
  }

#pragma unroll 1
  for (int t = 0; t < 8; ++t) {                  // 8 x 64 = 512-col chunk
    asm volatile("s_waitcnt vmcnt(12)" ::: "memory");  // Bq(t) landed
    __builtin_amdgcn_s_barrier();
    __builtin_amdgcn_sched_barrier(0);

    // ---- phase 1Q: Qt[192][64] = wq @ Bq (contraction 192)
    {
      f4 acc[3][4];
#pragma unroll
      for (int i = 0; i < 3; ++i)
#pragma unroll
        for (int j = 0; j < 4; ++j) acc[i][j] = (f4){0.f, 0.f, 0.f, 0.f};
#pragma unroll 2
      for (int kk = 0; kk < 192; kk += 32) {
        s8 af[3], bf[4];
#pragma unroll
        for (int mi = 0; mi < 3; ++mi)
          af[mi] = *(const s8*)(wqb +
              (long)(hg * 192 + w * 48 + mi * 16 + l15) * 192 + kk + lhi * 8);
#pragma unroll
        for (int ni = 0; ni < 4; ++ni) {
          const int s_ = ni * 16 + l15;
          bf[ni] = *(const s8*)(&Bq[s_ * 192 +
                                    ((((kk >> 3) + lhi) ^ (s_ & 7)) << 3)]);
        }
#pragma unroll
        for (int mi = 0; mi < 3; ++mi)
#pragma unroll
          for (int ni = 0; ni < 4; ++ni)
            acc[mi][ni] = __builtin_amdgcn_mfma_f32_16x16x32_bf16(
                af[mi], bf[ni], acc[mi][ni], 0, 0, 0);
      }
#pragma unroll
      for (int mi = 0; mi < 3; ++mi)
#pragma unroll
        for (int r = 0; r < 4; ++r) {
          const int row = w * 48 + mi * 16 + lhi * 4 + r;
#pragma unroll
          for (int ni = 0; ni < 4; ++ni) {
            const int col = ni * 16 + l15;
            const float v = acc[mi][ni][r];
            Qt[row * 64 + (((col >> 3) ^ (row & 7)) << 3) + (col & 7)] =
                f2bf(v);
            sqa[mi * 4 + r] += v * v;
          }
        }
    }

    asm volatile("s_waitcnt vmcnt(0)" ::: "memory");   // Bx(t) landed
    __builtin_amdgcn_s_barrier();
    __builtin_amdgcn_sched_barrier(0);

    // ---- phase 1K: Kt[192][64] = wk @ Bx (contraction 384)
    {
      f4 acc[3][4];
#pragma unroll
      for (int i = 0; i < 3; ++i)
#pragma unroll
        for (int j = 0; j < 4; ++j) acc[i][j] = (f4){0.f, 0.f, 0.f, 0.f};
#pragma unroll 2
      for (int kk = 0; kk < 384; kk += 32) {
        s8 af[3], bf[4];
#pragma unroll
        for (int mi = 0; mi < 3; ++mi)
          af[mi] = *(const s8*)(wkb +
              (long)(hg * 192 + w * 48 + mi * 16 + l15) * 384 + kk + lhi * 8);
#pragma unroll
        for (int ni = 0; ni < 4; ++ni) {
          const int s_ = ni * 16 + l15;
          bf[ni] = *(const s8*)(&Bx[s_ * 384 +
                                    ((((kk >> 3) + lhi) ^ (s_ & 7)) << 3)]);
        }
#pragma unroll
        for (int mi = 0; mi < 3; ++mi)
#pragma unroll
          for (int ni = 0; ni < 4; ++ni)
            acc[mi][ni] = __builtin_amdgcn_mfma_f32_16x16x32_bf16(
                af[mi], bf[ni], acc[mi][ni], 0, 0, 0);
      }
#pragma unroll
      for (int mi = 0; mi < 3; ++mi)
#pragma unroll
        for (int r = 0; r < 4; ++r) {
          const int row = w * 48 + mi * 16 + lhi * 4 + r;
#pragma unroll
          for (int ni = 0; ni < 4; ++ni) {
            const int col = ni * 16 + l15;
            const float v = acc[mi][ni][r];
            Kt[row * 64 + (((col >> 3) ^ (row & 7)) << 3) + (col & 7)] =
                f2bf(v);
            ska[mi * 4 + r] += v * v;
          }
        }
    }

    // all waves done reading Bq/Bx (their ds_reads were consumed by MFMAs)
    __builtin_amdgcn_s_barrier();

    // issue stage(t+1) NOW: latency hides under QK^T + next phase-1Q
    if (t + 1 < 8) {
      const long so = (long)(t + 1) * 64;
#pragma unroll
      for (int i = 0; i < 6; ++i) {
        const int q = i * 256 + tid, row = q / 24, c = q % 24;
        gl16(qTb + (so + row) * 192 + ((c ^ (row & 7)) * 8), &Bq[q * 8]);
      }
#pragma unroll
      for (int i = 0; i < 12; ++i) {
        const int q = i * 256 + tid, row = q / 48, c = q % 48;
        gl16(xTb + (so + row) * 384 + ((c ^ (row & 7)) * 8), &Bx[q * 8]);
      }
    }

    // ---- phase 2: QK^T (k=64), reads only rows this wave wrote
    {
      const int hl = w * 48;
#pragma unroll
      for (int kk = 0; kk < 64; kk += 32) {
        s8 qa[3], ka[3];
#pragma unroll
        for (int i = 0; i < 3; ++i) {
          const int rr = hl + i * 16 + l15;
          const int cb = (((kk >> 3) + lhi) ^ (rr & 7)) << 3;
          qa[i] = *(const s8*)(&Qt[rr * 64 + cb]);
          ka[i] = *(const s8*)(&Kt[rr * 64 + cb]);
        }
#pragma unroll
        for (int mi = 0; mi < 3; ++mi)
#pragma unroll
          for (int ni = 0; ni < 3; ++ni)
            Sacc[mi][ni] = __builtin_amdgcn_mfma_f32_16x16x32_bf16(
                qa[mi], ka[ni], Sacc[mi][ni], 0, 0, 0);
      }
    }
  }

  // ---- block epilogue: sumsq reduction + S-partial store (non-atomic)
#pragma unroll
  for (int mi = 0; mi < 3; ++mi)
#pragma unroll
    for (int r = 0; r < 4; ++r) {
      float tq = sqa[mi * 4 + r], tk = ska[mi * 4 + r];
      tq += __shfl_xor(tq, 1); tq += __shfl_xor(tq, 2);
      tq += __shfl_xor(tq, 4); tq += __shfl_xor(tq, 8);
      tk += __shfl_xor(tk, 1); tk += __shfl_xor(tk, 2);
      tk += __shfl_xor(tk, 4); tk += __shfl_xor(tk, 8);
      const int row = hg * 192 + w * 48 + mi * 16 + lhi * 4 + r;
      if (l15 == 0) {
        atomicAdd(&ssq[b * 384 + row], tq);
        atomicAdd(&ssk[b * 384 + row], tk);
      }
    }
  float* Sp = Spart + (((long)sc * 16 + b) * 8 + hg * 4 + w) * 2304;
#pragma unroll
  for (int mi = 0; mi < 3; ++mi)
#pragma unroll
    for (int ni = 0; ni < 3; ++ni)
#pragma unroll
      for (int r = 0; r < 4; ++r)
        Sp[(mi * 16 + lhi * 4 + r) * 48 + ni * 16 + l15] = Sacc[mi][ni][r];
}

// ---------------------------------------------------------------------------
// MFMA GEMM (R5 structure): 128x128 tile, 2-deep counted-vmcnt, T2 swizzle.
// Used for N (=Y@wv^T) and out (=N@xT^T).
// ---------------------------------------------------------------------------
template<int NKT, bool OUTF32, bool SWZ>
__global__ __launch_bounds__(256)
void gemm4(const short* __restrict__ A_, long Asb, int lda,
           const short* __restrict__ B_, long Bsb, int ldb,
           void* __restrict__ O_, long Osb, int ldo,
           int nbm, int nbn) {
  __shared__ __align__(16) short As[2][8192];
  __shared__ __align__(16) short Bs[2][8192];
  int f = blockIdx.x;
  if (SWZ) { const int cpx = gridDim.x >> 3; f = (f & 7) * cpx + (f >> 3); }
  const int m0 = (f % nbm) * 128;
  const int t2 = f / nbm;
  const int n0 = (t2 % nbn) * 128;
  const int bz = t2 / nbn;
  const short* Ag = A_ + (long)bz * Asb;
  const short* Bg = B_ + (long)bz * Bsb;

  const int tid = threadIdx.x, lane = tid & 63, wid = tid >> 6;
  const int l15 = lane & 15, lhi = lane >> 4;
  const int wm = (wid >> 1) * 64, wn = (wid & 1) * 64;
  const int srow = tid >> 3;
  const int skc = ((tid & 7) ^ (srow & 7)) * 8;

  f4 acc[4][4];
#pragma unroll
  for (int i = 0; i < 4; ++i)
#pragma unroll
    for (int j = 0; j < 4; ++j) acc[i][j] = (f4){0.f, 0.f, 0.f, 0.f};

#pragma unroll
  for (int it = 0; it < 4; ++it) {
    const int r = it * 32 + srow;
    gl16(Ag + (long)(m0 + r) * lda + skc, &As[0][(it * 256 + tid) * 8]);
    gl16(Bg + (long)(n0 + r) * ldb + skc, &Bs[0][(it * 256 + tid) * 8]);
  }
  if (NKT > 1) {
#pragma unroll
    for (int it = 0; it < 4; ++it) {
      const int r = it * 32 + srow;
      gl16(Ag + (long)(m0 + r) * lda + 64 + skc, &As[1][(it * 256 + tid) * 8]);
      gl16(Bg + (long)(n0 + r) * ldb + 64 + skc, &Bs[1][(it * 256 + tid) * 8]);
    }
  }

#pragma unroll
  for (int kt = 0; kt < NKT; ++kt) {
    const int cur = kt & 1;
    if (kt + 1 < NKT) asm volatile("s_waitcnt vmcnt(8)" ::: "memory");
    else              asm volatile("s_waitcnt vmcnt(0)" ::: "memory");
    __builtin_amdgcn_s_barrier();
    __builtin_amdgcn_sched_barrier(0);
#pragma unroll
    for (int kk = 0; kk < 2; ++kk) {
      const int cb = ((lhi + kk * 4) ^ (l15 & 7)) * 8;
      s8 af[4], bf[4];
#pragma unroll
      for (int i = 0; i < 4; ++i) {
        af[i] = *(const s8*)(&As[cur][(wm + i * 16 + l15) * 64 + cb]);
        bf[i] = *(const s8*)(&Bs[cur][(wn + i * 16 + l15) * 64 + cb]);
      }
#pragma unroll
      for (int mi = 0; mi < 4; ++mi)
#pragma unroll
        for (int ni = 0; ni < 4; ++ni)
          acc[mi][ni] = __builtin_amdgcn_mfma_f32_16x16x32_bf16(
              af[mi], bf[ni], acc[mi][ni], 0, 0, 0);
    }
    asm volatile("s_waitcnt lgkmcnt(0)" ::: "memory");
    __builtin_amdgcn_s_barrier();
    if (kt + 2 < NKT) {
      const int k2 = (kt + 2) * 64;
#pragma unroll
      for (int it = 0; it < 4; ++it) {
        const int r = it * 32 + srow;
        gl16(Ag + (long)(m0 + r) * lda + k2 + skc,
             &As[cur][(it * 256 + tid) * 8]);
        gl16(Bg + (long)(n0 + r) * ldb + k2 + skc,
             &Bs[cur][(it * 256 + tid) * 8]);
      }
    }
  }

#pragma unroll
  for (int mi = 0; mi < 4; ++mi)
#pragma unroll
    for (int r = 0; r < 4; ++r) {
      const int grow = m0 + wm + mi * 16 + lhi * 4 + r;
#pragma unroll
      for (int ni = 0; ni < 4; ++ni) {
        const int col = n0 + wn + ni * 16 + l15;
        const float v = acc[mi][ni][r];
        if (OUTF32)
          ((float*)O_)[(long)bz * Osb + (long)grow * ldo + col] = v;
        else
          ((short*)O_)[(long)bz * Osb + (long)grow * ldo + col] = f2bf(v);
      }
    }
}

// ---------------------------------------------------------------------------
// Combined prep: roles 0-5: x -> xT[4096][384]; 6-8: q -> qT; role 9:
// weight casts (wk, wvT transposed, wq, wp) + zero ssq/ssk (wprep merged —
// rides free inside this HBM-bound launch, deletes one kernel gap).
// ---------------------------------------------------------------------------
__global__ __launch_bounds__(256)
void prep_k(const float* __restrict__ x, const float* __restrict__ q,
            const float* __restrict__ wkv, const float* __restrict__ wq,
            const float* __restrict__ wp, short* __restrict__ xT,
            short* __restrict__ qT, short* __restrict__ wkb,
            short* __restrict__ wvT, short* __restrict__ wqb,
            short* __restrict__ wpb, float* __restrict__ ssqk) {
  const int role = blockIdx.x;
  if (role == 9) {
    const int g = (blockIdx.z * 64 + blockIdx.y) * 256 + threadIdx.x; // <262144
    if (g < 12288) ssqk[g] = 0.f;
    for (int i = g; i < 516096; i += 262144) {
      if (i < 147456) {
        wkb[i] = f2bf(wkv[i]);
      } else if (i < 294912) {
        const int t = i - 147456;
        wvT[t] = f2bf(wkv[(384 + (t % 384)) * 384 + t / 384]);
      } else if (i < 368640) {
        wqb[i - 294912] = f2bf(wq[i - 294912]);
      } else {
        wpb[i - 368640] = f2bf(wp[i - 368640]);
      }
    }
    return;
  }
  __shared__ float Ls[64][65];
  const bool isQ = role >= 6;
  const int C = isQ ? 192 : 384;
  const int c0 = (isQ ? role - 6 : role) * 64;
  const int s0 = blockIdx.y * 64;
  const float* src = (isQ ? q : x) + (long)blockIdx.z * C * 4096;
  short* dst = (isQ ? qT : xT) + (long)blockIdx.z * 4096 * C;
  const int tid = threadIdx.x;
  const int rr = tid >> 4, cq = (tid & 15) * 4;
#pragma unroll
  for (int it = 0; it < 4; ++it) {
    const int r = it * 16 + rr;
    f4 v = *(const f4*)(src + (long)(c0 + r) * 4096 + s0 + cq);
    Ls[r][cq + 0] = v.x; Ls[r][cq + 1] = v.y;
    Ls[r][cq + 2] = v.z; Ls[r][cq + 3] = v.w;
  }
  __syncthreads();
#pragma unroll
  for (int it = 0; it < 4; ++it) {
    const int sr = it * 16 + rr;
    s4 o;
#pragma unroll
    for (int j = 0; j < 4; ++j) o[j] = f2bf(Ls[cq + j][sr]);
    *(s4*)(&dst[(long)(s0 + sr) * C + c0 + cq]) = o;
  }
}

// ---------------------------------------------------------------------------
// softmax + Y fusion per (b,h): reduce 8 z-partials, logits, row softmax ->
// P^T in LDS (c padded 48->64 with zeros); then Y[:,h*48+d] = wp[:,hblk]@P
// via MFMA. Head h is the only writer of Y's column block.
// ---------------------------------------------------------------------------
__global__ __launch_bounds__(256)
void smY_k(const float* __restrict__ Spart, const float* __restrict__ ssq,
           const float* __restrict__ ssk, const float* __restrict__ temp,
           const short* __restrict__ wpb, short* __restrict__ Yb) {
  const int b = blockIdx.x, h = blockIdx.y, tid = threadIdx.x;
  __shared__ float L[2304];
  __shared__ float rq[48], rk[48], mrow[48], irow[48];
  __shared__ __align__(16) short PTl[48 * 72];   // [d][c] padded ld=72
  if (tid < 48) {
    rq[tid] = 1.f / fmaxf(sqrtf(ssq[b * 384 + h * 48 + tid]), 1e-12f);
    rk[tid] = 1.f / fmaxf(sqrtf(ssk[b * 384 + h * 48 + tid]), 1e-12f);
  }
  __syncthreads();
  const float tp = temp[h];
  for (int i = tid; i < 2304; i += 256) {
    float v = 0.f;
#pragma unroll
    for (int z = 0; z < 8; ++z)
      v += Spart[(((long)z * 16 + b) * 8 + h) * 2304 + i];
    const int c = i / 48, d = i % 48;
    L[i] = v * rq[c] * rk[d] * tp;
  }
  __syncthreads();
  if (tid < 48) {
    float m = -1e30f;
    for (int d = 0; d < 48; ++d) m = fmaxf(m, L[tid * 48 + d]);
    float s = 0.f;
    for (int d = 0; d < 48; ++d) s += __expf(L[tid * 48 + d] - m);
    mrow[tid] = m;
    irow[tid] = 1.f / s;
  }
  __syncthreads();
  for (int i = tid; i < 48 * 72; i += 256) {
    const int d = i / 72, c = i % 72;
    float p = 0.f;
    if (c < 48) p = __expf(L[c * 48 + d] - mrow[c]) * irow[c];
    PTl[i] = f2bf(p);
  }
  __syncthreads();
  const int lane = tid & 63, w = tid >> 6;
  const int l15 = lane & 15, lhi = lane >> 4;
  f4 acc[6][3];
#pragma unroll
  for (int i = 0; i < 6; ++i)
#pragma unroll
    for (int j = 0; j < 3; ++j) acc[i][j] = (f4){0.f, 0.f, 0.f, 0.f};
#pragma unroll
  for (int kk = 0; kk < 2; ++kk) {
    s8 bf[3];
#pragma unroll
    for (int ni = 0; ni < 3; ++ni)
      bf[ni] = *(const s8*)(&PTl[(ni * 16 + l15) * 72 + kk * 32 + lhi * 8]);
#pragma unroll
    for (int mi = 0; mi < 6; ++mi) {
      const int row = w * 96 + mi * 16 + l15;
      s8 af = *(const s8*)(wpb + (long)row * 384 + h * 48 + kk * 32 + lhi * 8);
#pragma unroll
      for (int ni = 0; ni < 3; ++ni)
        acc[mi][ni] = __builtin_amdgcn_mfma_f32_16x16x32_bf16(
            af, bf[ni], acc[mi][ni], 0, 0, 0);
    }
  }
#pragma unroll
  for (int mi = 0; mi < 6; ++mi)
#pragma unroll
    for (int r = 0; r < 4; ++r) {
      const int row = w * 96 + mi * 16 + lhi * 4 + r;
#pragma unroll
      for (int ni = 0; ni < 3; ++ni) {
        const int d = ni * 16 + l15;
        Yb[((long)b * 384 + row) * 384 + h * 48 + d] = f2bf(acc[mi][ni][r]);
      }
    }
}

extern "C" void kernel_launch(void* const* d_in, const int* in_sizes, int n_in,
                              void* d_out, int out_size, void* d_ws, size_t ws_size,
                              hipStream_t stream) {
  const float* x = (const float*)d_in[0];
  const float* query = (const float*)d_in[1];
  const float* w_kv = (const float*)d_in[2];
  const float* w_q = (const float*)d_in[3];
  const float* w_proj = (const float*)d_in[4];
  const float* temp = (const float*)d_in[5];

  // workspace carve (~105 MB), all offsets 16B-aligned
  char* w = (char*)d_ws;
  short* xT   = (short*)(w + 0);            // [16][4096][384] bf16
  short* qT   = (short*)(w + 50331648);     // [16][4096][192] bf16
  float* Spart= (float*)(w + 75497472);     // [8][16][8][2304] f32
  short* Yb   = (short*)(w + 94371840);     // [16][384][384] bf16
  short* Nbb  = (short*)(w + 99090432);     // [16][384][384] bf16
  float* ssq  = (float*)(w + 103809024);    // [16][384] f32
  float* ssk  = (float*)(w + 103833600);    // [16][384] f32
  short* wkb  = (short*)(w + 103858176);
  short* wvT  = (short*)(w + 104153088);
  short* wqb  = (short*)(w + 104448000);
  short* wpb  = (short*)(w + 104595456);
  float* out  = (float*)d_out;

  // transposes + casts + weight prep + sumsq zeroing (one launch)
  prep_k<<<dim3(10, 64, 16), 256, 0, stream>>>(
      x, query, w_kv, w_q, w_proj, xT, qT, wkb, wvT, wqb, wpb, ssq);
  // fused K/Q GEMM + QK^T partials (+ sumsq), R8 geometry
  kqs_k<<<256, 256, 0, stream>>>(xT, qT, wkb, wqb, Spart, ssq, ssk);
  // softmax + Y = wp @ P  (per-head column block)
  smY_k<<<dim3(16, 8), 256, 0, stream>>>(Spart, ssq, ssk, temp, wpb, Yb);
  // N[o][j] = sum_d Y[o,d] wvT[j,d]
  gemm4<6, false, false><<<144, 256, 0, stream>>>(
      Yb, 147456, 384, wvT, 0, 384, Nbb, 147456, 384, 3, 3);
  // out[o][s] = sum_j N[o,j] xT[s,j]  (f32)
  gemm4<6, true, true><<<1536, 256, 0, stream>>>(
      Nbb, 147456, 384, xT, 1572864, 384, out, 1572864, 4096, 3, 32);
}

// Round 15
// 188.939 us; speedup vs baseline: 1.6621x; 1.0045x over previous
//
#include <hip/hip_runtime.h>
#include <hip/hip_bf16.h>

typedef float f4 __attribute__((ext_vector_type(4)));
typedef short s8 __attribute__((ext_vector_type(8)));
typedef short s4 __attribute__((ext_vector_type(4)));

__device__ __forceinline__ short f2bf(float f) {
  union { float f; unsigned u; } v; v.f = f;
  unsigned r = v.u + 0x7fffu + ((v.u >> 16) & 1u);
  return (short)(r >> 16);
}
// async global->LDS, 16B/lane; LDS dest = wave-uniform base + lane*16 (linear)
__device__ __forceinline__ void gl16(const short* g, short* l) {
  __builtin_amdgcn_global_load_lds(
      (const __attribute__((address_space(1))) unsigned*)g,
      (__attribute__((address_space(3))) unsigned*)l, 16, 0, 0);
}

// ---------------------------------------------------------------------------
// FUSED K-GEMM + Q-GEMM + QK^T (R8 geometry — measured optimum ~98 us).
//  grid = 256 (1 block/CU), block = (b, sc in [0,8), hg); 8 slices x 64 cols.
//  LDS 120 KB: Bq[64][192], Bx[64][384] (XOR-swizzled via pre-swizzled
//  global source, rule-21), Qt/Kt[192][64] (XOR-swizzled write+read).
//  Register S-acc (48x48/wave), no S atomics; sumsq in regs, one atomic
//  set per block. N=64 slices keep the weight-load:MFMA ratio low.
//  [Ablation R9-R13: narrower slices -21us (weight ratio), no-LDS B -123us
//  (4.6x FETCH + FIFO vmcnt), 8-wave/147KB -51us (staging cover + FETCH).
//  Constraints are mutually binding at 120 KB -> 1 wave/SIMD plateau.]
// ---------------------------------------------------------------------------
__global__ __launch_bounds__(256, 1)
void kqs_k(const short* __restrict__ xT, const short* __restrict__ qT,
           const short* __restrict__ wkb, const short* __restrict__ wqb,
           float* __restrict__ Spart, float* __restrict__ ssq,
           float* __restrict__ ssk) {
  __shared__ __align__(16) short Bq[64 * 192];   // 24 KB
  __shared__ __align__(16) short Bx[64 * 384];   // 48 KB
  __shared__ __align__(16) short Qt[192 * 64];   // 24 KB
  __shared__ __align__(16) short Kt[192 * 64];   // 24 KB
  const int orig = blockIdx.x;
  const int xcd = orig & 7, ix = orig >> 3;      // ix in [0,32)
  const int pair = xcd * 16 + (ix >> 1);         // [0,128): (b, sc)
  const int hg = ix & 1;
  const int b = pair >> 3, sc = pair & 7;
  const int tid = threadIdx.x, lane = tid & 63, w = tid >> 6;
  const int l15 = lane & 15, lhi = lane >> 4;

  const short* qTb = qT + ((long)b * 4096 + sc * 512) * 192;
  const short* xTb = xT + ((long)b * 4096 + sc * 512) * 384;

  f4 Sacc[3][3];
#pragma unroll
  for (int i = 0; i < 3; ++i)
#pragma unroll
    for (int j = 0; j < 3; ++j) Sacc[i][j] = (f4){0.f, 0.f, 0.f, 0.f};
  float sqa[12], ska[12];
#pragma unroll
  for (int i = 0; i < 12; ++i) { sqa[i] = 0.f; ska[i] = 0.f; }

  // prologue: stage slice 0 (Bq: 6 gl16/thread, then Bx: 12)
#pragma unroll
  for (int i = 0; i < 6; ++i) {
    const int q = i * 256 + tid, row = q / 24, c = q % 24;
    gl16(qTb + row * 192 + ((c ^ (row & 7)) * 8), &Bq[q * 8]);
  }
#pragma unroll
  for (int i = 0; i < 12; ++i) {
    const int q = i * 256 + tid, row = q / 48, c = q % 48;
    gl16(xTb + row * 384 + ((c ^ (row & 7)) * 8), &Bx[q * 8]);
  }

#pragma unroll 1
  for (int t = 0; t < 8; ++t) {                  // 8 x 64 = 512-col chunk
    asm volatile("s_waitcnt vmcnt(12)" ::: "memory");  // Bq(t) landed
    __builtin_amdgcn_s_barrier();
    __builtin_amdgcn_sched_barrier(0);

    // ---- phase 1Q: Qt[192][64] = wq @ Bq (contraction 192)
    {
      f4 acc[3][4];
#pragma unroll
      for (int i = 0; i < 3; ++i)
#pragma unroll
        for (int j = 0; j < 4; ++j) acc[i][j] = (f4){0.f, 0.f, 0.f, 0.f};
#pragma unroll 2
      for (int kk = 0; kk < 192; kk += 32) {
        s8 af[3], bf[4];
#pragma unroll
        for (int mi = 0; mi < 3; ++mi)
          af[mi] = *(const s8*)(wqb +
              (long)(hg * 192 + w * 48 + mi * 16 + l15) * 192 + kk + lhi * 8);
#pragma unroll
        for (int ni = 0; ni < 4; ++ni) {
          const int s_ = ni * 16 + l15;
          bf[ni] = *(const s8*)(&Bq[s_ * 192 +
                                    ((((kk >> 3) + lhi) ^ (s_ & 7)) << 3)]);
        }
#pragma unroll
        for (int mi = 0; mi < 3; ++mi)
#pragma unroll
          for (int ni = 0; ni < 4; ++ni)
            acc[mi][ni] = __builtin_amdgcn_mfma_f32_16x16x32_bf16(
                af[mi], bf[ni], acc[mi][ni], 0, 0, 0);
      }
#pragma unroll
      for (int mi = 0; mi < 3; ++mi)
#pragma unroll
        for (int r = 0; r < 4; ++r) {
          const int row = w * 48 + mi * 16 + lhi * 4 + r;
#pragma unroll
          for (int ni = 0; ni < 4; ++ni) {
            const int col = ni * 16 + l15;
            const float v = acc[mi][ni][r];
            Qt[row * 64 + (((col >> 3) ^ (row & 7)) << 3) + (col & 7)] =
                f2bf(v);
            sqa[mi * 4 + r] += v * v;
          }
        }
    }

    asm volatile("s_waitcnt vmcnt(0)" ::: "memory");   // Bx(t) landed
    __builtin_amdgcn_s_barrier();
    __builtin_amdgcn_sched_barrier(0);

    // ---- phase 1K: Kt[192][64] = wk @ Bx (contraction 384)
    {
      f4 acc[3][4];
#pragma unroll
      for (int i = 0; i < 3; ++i)
#pragma unroll
        for (int j = 0; j < 4; ++j) acc[i][j] = (f4){0.f, 0.f, 0.f, 0.f};
#pragma unroll 2
      for (int kk = 0; kk < 384; kk += 32) {
        s8 af[3], bf[4];
#pragma unroll
        for (int mi = 0; mi < 3; ++mi)
          af[mi] = *(const s8*)(wkb +
              (long)(hg * 192 + w * 48 + mi * 16 + l15) * 384 + kk + lhi * 8);
#pragma unroll
        for (int ni = 0; ni < 4; ++ni) {
          const int s_ = ni * 16 + l15;
          bf[ni] = *(const s8*)(&Bx[s_ * 384 +
                                    ((((kk >> 3) + lhi) ^ (s_ & 7)) << 3)]);
        }
#pragma unroll
        for (int mi = 0; mi < 3; ++mi)
#pragma unroll
          for (int ni = 0; ni < 4; ++ni)
            acc[mi][ni] = __builtin_amdgcn_mfma_f32_16x16x32_bf16(
                af[mi], bf[ni], acc[mi][ni], 0, 0, 0);
      }
#pragma unroll
      for (int mi = 0; mi < 3; ++mi)
#pragma unroll
        for (int r = 0; r < 4; ++r) {
          const int row = w * 48 + mi * 16 + lhi * 4 + r;
#pragma unroll
          for (int ni = 0; ni < 4; ++ni) {
            const int col = ni * 16 + l15;
            const float v = acc[mi][ni][r];
            Kt[row * 64 + (((col >> 3) ^ (row & 7)) << 3) + (col & 7)] =
                f2bf(v);
            ska[mi * 4 + r] += v * v;
          }
        }
    }

    // all waves done reading Bq/Bx (their ds_reads were consumed by MFMAs)
    __builtin_amdgcn_s_barrier();

    // issue stage(t+1) NOW: latency hides under QK^T + next phase-1Q
    if (t + 1 < 8) {
      const long so = (long)(t + 1) * 64;
#pragma unroll
      for (int i = 0; i < 6; ++i) {
        const int q = i * 256 + tid, row = q / 24, c = q % 24;
        gl16(qTb + (so + row) * 192 + ((c ^ (row & 7)) * 8), &Bq[q * 8]);
      }
#pragma unroll
      for (int i = 0; i < 12; ++i) {
        const int q = i * 256 + tid, row = q / 48, c = q % 48;
        gl16(xTb + (so + row) * 384 + ((c ^ (row & 7)) * 8), &Bx[q * 8]);
      }
    }

    // ---- phase 2: QK^T (k=64), reads only rows this wave wrote
    {
      const int hl = w * 48;
#pragma unroll
      for (int kk = 0; kk < 64; kk += 32) {
        s8 qa[3], ka[3];
#pragma unroll
        for (int i = 0; i < 3; ++i) {
          const int rr = hl + i * 16 + l15;
          const int cb = (((kk >> 3) + lhi) ^ (rr & 7)) << 3;
          qa[i] = *(const s8*)(&Qt[rr * 64 + cb]);
          ka[i] = *(const s8*)(&Kt[rr * 64 + cb]);
        }
#pragma unroll
        for (int mi = 0; mi < 3; ++mi)
#pragma unroll
          for (int ni = 0; ni < 3; ++ni)
            Sacc[mi][ni] = __builtin_amdgcn_mfma_f32_16x16x32_bf16(
                qa[mi], ka[ni], Sacc[mi][ni], 0, 0, 0);
      }
    }
  }

  // ---- block epilogue: sumsq reduction + S-partial store (non-atomic)
#pragma unroll
  for (int mi = 0; mi < 3; ++mi)
#pragma unroll
    for (int r = 0; r < 4; ++r) {
      float tq = sqa[mi * 4 + r], tk = ska[mi * 4 + r];
      tq += __shfl_xor(tq, 1); tq += __shfl_xor(tq, 2);
      tq += __shfl_xor(tq, 4); tq += __shfl_xor(tq, 8);
      tk += __shfl_xor(tk, 1); tk += __shfl_xor(tk, 2);
      tk += __shfl_xor(tk, 4); tk += __shfl_xor(tk, 8);
      const int row = hg * 192 + w * 48 + mi * 16 + lhi * 4 + r;
      if (l15 == 0) {
        atomicAdd(&ssq[b * 384 + row], tq);
        atomicAdd(&ssk[b * 384 + row], tk);
      }
    }
  float* Sp = Spart + (((long)sc * 16 + b) * 8 + hg * 4 + w) * 2304;
#pragma unroll
  for (int mi = 0; mi < 3; ++mi)
#pragma unroll
    for (int ni = 0; ni < 3; ++ni)
#pragma unroll
      for (int r = 0; r < 4; ++r)
        Sp[(mi * 16 + lhi * 4 + r) * 48 + ni * 16 + l15] = Sacc[mi][ni][r];
}

// ---------------------------------------------------------------------------
// MFMA GEMM (R5 structure): 128x128 tile, 2-deep counted-vmcnt, T2 swizzle.
// Used for N (=Y@wv^T) and out (=N@xT^T).
// ---------------------------------------------------------------------------
template<int NKT, bool OUTF32, bool SWZ>
__global__ __launch_bounds__(256)
void gemm4(const short* __restrict__ A_, long Asb, int lda,
           const short* __restrict__ B_, long Bsb, int ldb,
           void* __restrict__ O_, long Osb, int ldo,
           int nbm, int nbn) {
  __shared__ __align__(16) short As[2][8192];
  __shared__ __align__(16) short Bs[2][8192];
  int f = blockIdx.x;
  if (SWZ) { const int cpx = gridDim.x >> 3; f = (f & 7) * cpx + (f >> 3); }
  const int m0 = (f % nbm) * 128;
  const int t2 = f / nbm;
  const int n0 = (t2 % nbn) * 128;
  const int bz = t2 / nbn;
  const short* Ag = A_ + (long)bz * Asb;
  const short* Bg = B_ + (long)bz * Bsb;

  const int tid = threadIdx.x, lane = tid & 63, wid = tid >> 6;
  const int l15 = lane & 15, lhi = lane >> 4;
  const int wm = (wid >> 1) * 64, wn = (wid & 1) * 64;
  const int srow = tid >> 3;
  const int skc = ((tid & 7) ^ (srow & 7)) * 8;

  f4 acc[4][4];
#pragma unroll
  for (int i = 0; i < 4; ++i)
#pragma unroll
    for (int j = 0; j < 4; ++j) acc[i][j] = (f4){0.f, 0.f, 0.f, 0.f};

#pragma unroll
  for (int it = 0; it < 4; ++it) {
    const int r = it * 32 + srow;
    gl16(Ag + (long)(m0 + r) * lda + skc, &As[0][(it * 256 + tid) * 8]);
    gl16(Bg + (long)(n0 + r) * ldb + skc, &Bs[0][(it * 256 + tid) * 8]);
  }
  if (NKT > 1) {
#pragma unroll
    for (int it = 0; it < 4; ++it) {
      const int r = it * 32 + srow;
      gl16(Ag + (long)(m0 + r) * lda + 64 + skc, &As[1][(it * 256 + tid) * 8]);
      gl16(Bg + (long)(n0 + r) * ldb + 64 + skc, &Bs[1][(it * 256 + tid) * 8]);
    }
  }

#pragma unroll
  for (int kt = 0; kt < NKT; ++kt) {
    const int cur = kt & 1;
    if (kt + 1 < NKT) asm volatile("s_waitcnt vmcnt(8)" ::: "memory");
    else              asm volatile("s_waitcnt vmcnt(0)" ::: "memory");
    __builtin_amdgcn_s_barrier();
    __builtin_amdgcn_sched_barrier(0);
#pragma unroll
    for (int kk = 0; kk < 2; ++kk) {
      const int cb = ((lhi + kk * 4) ^ (l15 & 7)) * 8;
      s8 af[4], bf[4];
#pragma unroll
      for (int i = 0; i < 4; ++i) {
        af[i] = *(const s8*)(&As[cur][(wm + i * 16 + l15) * 64 + cb]);
        bf[i] = *(const s8*)(&Bs[cur][(wn + i * 16 + l15) * 64 + cb]);
      }
#pragma unroll
      for (int mi = 0; mi < 4; ++mi)
#pragma unroll
        for (int ni = 0; ni < 4; ++ni)
          acc[mi][ni] = __builtin_amdgcn_mfma_f32_16x16x32_bf16(
              af[mi], bf[ni], acc[mi][ni], 0, 0, 0);
    }
    asm volatile("s_waitcnt lgkmcnt(0)" ::: "memory");
    __builtin_amdgcn_s_barrier();
    if (kt + 2 < NKT) {
      const int k2 = (kt + 2) * 64;
#pragma unroll
      for (int it = 0; it < 4; ++it) {
        const int r = it * 32 + srow;
        gl16(Ag + (long)(m0 + r) * lda + k2 + skc,
             &As[cur][(it * 256 + tid) * 8]);
        gl16(Bg + (long)(n0 + r) * ldb + k2 + skc,
             &Bs[cur][(it * 256 + tid) * 8]);
      }
    }
  }

#pragma unroll
  for (int mi = 0; mi < 4; ++mi)
#pragma unroll
    for (int r = 0; r < 4; ++r) {
      const int grow = m0 + wm + mi * 16 + lhi * 4 + r;
#pragma unroll
      for (int ni = 0; ni < 4; ++ni) {
        const int col = n0 + wn + ni * 16 + l15;
        const float v = acc[mi][ni][r];
        if (OUTF32)
          ((float*)O_)[(long)bz * Osb + (long)grow * ldo + col] = v;
        else
          ((short*)O_)[(long)bz * Osb + (long)grow * ldo + col] = f2bf(v);
      }
    }
}

// ---------------------------------------------------------------------------
// Combined prep: roles 0-5: x -> xT[4096][384]; 6-8: q -> qT; role 9:
// weight casts (wk, wvT transposed, wq, wp) + zero ssq/ssk (wprep merged —
// rides free inside this HBM-bound launch, deletes one kernel gap).
// ---------------------------------------------------------------------------
__global__ __launch_bounds__(256)
void prep_k(const float* __restrict__ x, const float* __restrict__ q,
            const float* __restrict__ wkv, const float* __restrict__ wq,
            const float* __restrict__ wp, short* __restrict__ xT,
            short* __restrict__ qT, short* __restrict__ wkb,
            short* __restrict__ wvT, short* __restrict__ wqb,
            short* __restrict__ wpb, float* __restrict__ ssqk) {
  const int role = blockIdx.x;
  if (role == 9) {
    const int g = (blockIdx.z * 64 + blockIdx.y) * 256 + threadIdx.x; // <262144
    if (g < 12288) ssqk[g] = 0.f;
    for (int i = g; i < 516096; i += 262144) {
      if (i < 147456) {
        wkb[i] = f2bf(wkv[i]);
      } else if (i < 294912) {
        const int t = i - 147456;
        wvT[t] = f2bf(wkv[(384 + (t % 384)) * 384 + t / 384]);
      } else if (i < 368640) {
        wqb[i - 294912] = f2bf(wq[i - 294912]);
      } else {
        wpb[i - 368640] = f2bf(wp[i - 368640]);
      }
    }
    return;
  }
  __shared__ float Ls[64][65];
  const bool isQ = role >= 6;
  const int C = isQ ? 192 : 384;
  const int c0 = (isQ ? role - 6 : role) * 64;
  const int s0 = blockIdx.y * 64;
  const float* src = (isQ ? q : x) + (long)blockIdx.z * C * 4096;
  short* dst = (isQ ? qT : xT) + (long)blockIdx.z * 4096 * C;
  const int tid = threadIdx.x;
  const int rr = tid >> 4, cq = (tid & 15) * 4;
#pragma unroll
  for (int it = 0; it < 4; ++it) {
    const int r = it * 16 + rr;
    f4 v = *(const f4*)(src + (long)(c0 + r) * 4096 + s0 + cq);
    Ls[r][cq + 0] = v.x; Ls[r][cq + 1] = v.y;
    Ls[r][cq + 2] = v.z; Ls[r][cq + 3] = v.w;
  }
  __syncthreads();
#pragma unroll
  for (int it = 0; it < 4; ++it) {
    const int sr = it * 16 + rr;
    s4 o;
#pragma unroll
    for (int j = 0; j < 4; ++j) o[j] = f2bf(Ls[cq + j][sr]);
    *(s4*)(&dst[(long)(s0 + sr) * C + c0 + cq]) = o;
  }
}

// ---------------------------------------------------------------------------
// softmax + Y fusion per (b,h): reduce 8 z-partials, logits, row softmax ->
// P^T in LDS (c padded 48->64 with zeros); then Y[:,h*48+d] = wp[:,hblk]@P
// via MFMA. Head h is the only writer of Y's column block.
// ---------------------------------------------------------------------------
__global__ __launch_bounds__(256)
void smY_k(const float* __restrict__ Spart, const float* __restrict__ ssq,
           const float* __restrict__ ssk, const float* __restrict__ temp,
           const short* __restrict__ wpb, short* __restrict__ Yb) {
  const int b = blockIdx.x, h = blockIdx.y, tid = threadIdx.x;
  __shared__ float L[2304];
  __shared__ float rq[48], rk[48], mrow[48], irow[48];
  __shared__ __align__(16) short PTl[48 * 72];   // [d][c] padded ld=72
  if (tid < 48) {
    rq[tid] = 1.f / fmaxf(sqrtf(ssq[b * 384 + h * 48 + tid]), 1e-12f);
    rk[tid] = 1.f / fmaxf(sqrtf(ssk[b * 384 + h * 48 + tid]), 1e-12f);
  }
  __syncthreads();
  const float tp = temp[h];
  for (int i = tid; i < 2304; i += 256) {
    float v = 0.f;
#pragma unroll
    for (int z = 0; z < 8; ++z)
      v += Spart[(((long)z * 16 + b) * 8 + h) * 2304 + i];
    const int c = i / 48, d = i % 48;
    L[i] = v * rq[c] * rk[d] * tp;
  }
  __syncthreads();
  if (tid < 48) {
    float m = -1e30f;
    for (int d = 0; d < 48; ++d) m = fmaxf(m, L[tid * 48 + d]);
    float s = 0.f;
    for (int d = 0; d < 48; ++d) s += __expf(L[tid * 48 + d] - m);
    mrow[tid] = m;
    irow[tid] = 1.f / s;
  }
  __syncthreads();
  for (int i = tid; i < 48 * 72; i += 256) {
    const int d = i / 72, c = i % 72;
    float p = 0.f;
    if (c < 48) p = __expf(L[c * 48 + d] - mrow[c]) * irow[c];
    PTl[i] = f2bf(p);
  }
  __syncthreads();
  const int lane = tid & 63, w = tid >> 6;
  const int l15 = lane & 15, lhi = lane >> 4;
  f4 acc[6][3];
#pragma unroll
  for (int i = 0; i < 6; ++i)
#pragma unroll
    for (int j = 0; j < 3; ++j) acc[i][j] = (f4){0.f, 0.f, 0.f, 0.f};
#pragma unroll
  for (int kk = 0; kk < 2; ++kk) {
    s8 bf[3];
#pragma unroll
    for (int ni = 0; ni < 3; ++ni)
      bf[ni] = *(const s8*)(&PTl[(ni * 16 + l15) * 72 + kk * 32 + lhi * 8]);
#pragma unroll
    for (int mi = 0; mi < 6; ++mi) {
      const int row = w * 96 + mi * 16 + l15;
      s8 af = *(const s8*)(wpb + (long)row * 384 + h * 48 + kk * 32 + lhi * 8);
#pragma unroll
      for (int ni = 0; ni < 3; ++ni)
        acc[mi][ni] = __builtin_amdgcn_mfma_f32_16x16x32_bf16(
            af, bf[ni], acc[mi][ni], 0, 0, 0);
    }
  }
#pragma unroll
  for (int mi = 0; mi < 6; ++mi)
#pragma unroll
    for (int r = 0; r < 4; ++r) {
      const int row = w * 96 + mi * 16 + lhi * 4 + r;
#pragma unroll
      for (int ni = 0; ni < 3; ++ni) {
        const int d = ni * 16 + l15;
        Yb[((long)b * 384 + row) * 384 + h * 48 + d] = f2bf(acc[mi][ni][r]);
      }
    }
}

extern "C" void kernel_launch(void* const* d_in, const int* in_sizes, int n_in,
                              void* d_out, int out_size, void* d_ws, size_t ws_size,
                              hipStream_t stream) {
  const float* x = (const float*)d_in[0];
  const float* query = (const float*)d_in[1];
  const float* w_kv = (const float*)d_in[2];
  const float* w_q = (const float*)d_in[3];
  const float* w_proj = (const float*)d_in[4];
  const float* temp = (const float*)d_in[5];

  // workspace carve (~105 MB), all offsets 16B-aligned
  char* w = (char*)d_ws;
  short* xT   = (short*)(w + 0);            // [16][4096][384] bf16
  short* qT   = (short*)(w + 50331648);     // [16][4096][192] bf16
  float* Spart= (float*)(w + 75497472);     // [8][16][8][2304] f32
  short* Yb   = (short*)(w + 94371840);     // [16][384][384] bf16
  short* Nbb  = (short*)(w + 99090432);     // [16][384][384] bf16
  float* ssq  = (float*)(w + 103809024);    // [16][384] f32
  float* ssk  = (float*)(w + 103833600);    // [16][384] f32
  short* wkb  = (short*)(w + 103858176);
  short* wvT  = (short*)(w + 104153088);
  short* wqb  = (short*)(w + 104448000);
  short* wpb  = (short*)(w + 104595456);
  float* out  = (float*)d_out;

  // transposes + casts + weight prep + sumsq zeroing (one launch)
  prep_k<<<dim3(10, 64, 16), 256, 0, stream>>>(
      x, query, w_kv, w_q, w_proj, xT, qT, wkb, wvT, wqb, wpb, ssq);
  // fused K/Q GEMM + QK^T partials (+ sumsq), R8 geometry
  kqs_k<<<256, 256, 0, stream>>>(xT, qT, wkb, wqb, Spart, ssq, ssk);
  // softmax + Y = wp @ P  (per-head column block)
  smY_k<<<dim3(16, 8), 256, 0, stream>>>(Spart, ssq, ssk, temp, wpb, Yb);
  // N[o][j] = sum_d Y[o,d] wvT[j,d]
  gemm4<6, false, false><<<144, 256, 0, stream>>>(
      Yb, 147456, 384, wvT, 0, 384, Nbb, 147456, 384, 3, 3);
  // out[o][s] = sum_j N[o,j] xT[s,j]  (f32)
  gemm4<6, true, true><<<1536, 256, 0, stream>>>(
      Nbb, 147456, 384, xT, 1572864, 384, out, 1572864, 4096, 3, 32);
}